// Round 10
// baseline (412.389 us; speedup 1.0000x reference)
//
#include <hip/hip_runtime.h>
#include <hip/hip_bf16.h>
#include <cstdint>
#include <cstddef>

typedef __bf16 bf16x8 __attribute__((ext_vector_type(8)));
typedef float f32x4 __attribute__((ext_vector_type(4)));
typedef float f32x16 __attribute__((ext_vector_type(16)));

#define MOD_SCALE 1.4731391e-02f   // 1/sqrt(512*9)
#define EPSF 1e-8f

// ---------------------------------------------------------------------------
// K1: s[b][i] = dot(style[b], mod_w[i]) + mod_b[i]
// ---------------------------------------------------------------------------
__global__ __launch_bounds__(512) void k_style(
    const float* __restrict__ style, const float* __restrict__ mod_w,
    const float* __restrict__ mod_b, float* __restrict__ s)
{
  __shared__ float st[512];
  const int b = blockIdx.x, i = threadIdx.x;
  st[i] = style[b*512 + i];
  __syncthreads();
  const float4* mw = (const float4*)(mod_w + (size_t)i*512);
  float acc = 0.f;
  #pragma unroll 8
  for (int j = 0; j < 128; ++j) {
    float4 v = mw[j];
    acc += v.x*st[4*j] + v.y*st[4*j+1] + v.z*st[4*j+2] + v.w*st[4*j+3];
  }
  s[b*512 + i] = acc + mod_b[i];
}

// ---------------------------------------------------------------------------
// K2: w2[o][i] = sum_kk weight^2 ; WF = bf16(SCALE*weight) in MFMA-fragment
// order: WF[kk*32 + cc*4 + ks][g][lane][e]  (o = g*32+(lane&31),
// ch = cc*64 + ks*16 + (lane>>5)*8 + e) — an A-frag load is one fully
// coalesced 1 KB global_load_dwordx4 per wave (lane l reads base + l*16).
// ---------------------------------------------------------------------------
__global__ __launch_bounds__(256) void k_weight(
    const float* __restrict__ weight, float* __restrict__ w2,
    __hip_bfloat16* __restrict__ WF)
{
  const int o = blockIdx.x, t = threadIdx.x;
  #pragma unroll
  for (int h = 0; h < 2; ++h) {
    const int i = t + h*256;
    const float* wp = weight + ((size_t)o*512 + i)*9;
    const int g = o >> 5;
    const int lane = (o & 31) | (((i >> 3) & 1) << 5);
    const int e = i & 7;
    const int cc = i >> 6, ks = (i >> 4) & 3;
    __hip_bfloat16* dst = WF + ((((size_t)(cc*4 + ks))*16 + g)*64 + lane)*8 + e;
    float sq = 0.f;
    #pragma unroll
    for (int kk = 0; kk < 9; ++kk) {
      float v = wp[kk];
      sq += v*v;
      dst[(size_t)kk*262144] = __float2bfloat16(v * MOD_SCALE);
    }
    w2[(size_t)o*512 + i] = sq;
  }
}

// ---------------------------------------------------------------------------
// K2b: demod[b][o] = rsqrt(SCALE^2 * sum_i s[b][i]^2 * w2[o][i] + eps)
// ---------------------------------------------------------------------------
__global__ __launch_bounds__(256) void k_demod(
    const float* __restrict__ s, const float* __restrict__ w2,
    float* __restrict__ demod)
{
  __shared__ float s2[512];
  const int b = blockIdx.x, t = threadIdx.x;
  {
    float a = s[b*512 + t];        s2[t]     = a*a;
    float c = s[b*512 + t + 256];  s2[t+256] = c*c;
  }
  __syncthreads();
  #pragma unroll
  for (int h = 0; h < 2; ++h) {
    const int o = t + h*256;
    const float4* wp = (const float4*)(w2 + (size_t)o*512);
    float acc = 0.f;
    #pragma unroll 8
    for (int j = 0; j < 128; ++j) {
      float4 v = wp[j];
      acc += v.x*s2[4*j] + v.y*s2[4*j+1] + v.z*s2[4*j+2] + v.w*s2[4*j+3];
    }
    demod[b*512 + o] = rsqrtf(MOD_SCALE*MOD_SCALE*acc + EPSF);
  }
}

// ---------------------------------------------------------------------------
// K3: Xm[b][py][px][i] = bf16(s[b][i] * x[b][i][py-1][px-1]); writes own halo.
// ---------------------------------------------------------------------------
__global__ __launch_bounds__(256) void k_xm(
    const float* __restrict__ x, const float* __restrict__ s,
    __hip_bfloat16* __restrict__ Xm)
{
  __shared__ __hip_bfloat16 T[64][40];
  const int bid = blockIdx.x;
  const int cb = bid & 15, y = (bid >> 4) & 63, b = bid >> 10;
  const int ic0 = cb*32;
  const int t = threadIdx.x;
  const int i = t >> 3, x0 = (t & 7)*8;
  const float sv = s[b*512 + ic0 + i];
  const float4* xp = (const float4*)(x + (size_t)(b*512 + ic0 + i)*4096 + y*64 + x0);
  float4 v0 = xp[0], v1 = xp[1];
  float vals[8] = {v0.x, v0.y, v0.z, v0.w, v1.x, v1.y, v1.z, v1.w};
  #pragma unroll
  for (int j = 0; j < 8; ++j) T[x0+j][i] = __float2bfloat16(vals[j]*sv);

  const float4 z4 = make_float4(0.f, 0.f, 0.f, 0.f);
  if (t < 8) {
    const int side = t >> 2, j = t & 3;
    float4* hz = (float4*)(Xm + (((size_t)(b*66 + (y+1))*66 + side*65)*512 + ic0 + j*8));
    *hz = z4;
  }
  if (y == 0) {
    for (int idx = t; idx < 264; idx += 256) {
      const int px = idx >> 2, j = idx & 3;
      float4* hz = (float4*)(Xm + (((size_t)(b*66 + 0)*66 + px)*512 + ic0 + j*8));
      *hz = z4;
    }
  }
  if (y == 63) {
    for (int idx = t; idx < 264; idx += 256) {
      const int px = idx >> 2, j = idx & 3;
      float4* hz = (float4*)(Xm + (((size_t)(b*66 + 65)*66 + px)*512 + ic0 + j*8));
      *hz = z4;
    }
  }

  __syncthreads();
  const int p = t >> 2, c = (t & 3)*8;
  __hip_bfloat16* dst = Xm + (((size_t)(b*66 + (y+1))*66 + (p+1))*512 + ic0 + c);
  *(float4*)dst = *(const float4*)&T[p][c];
}

// ---------------------------------------------------------------------------
// K4: conv as implicit GEMM, 256x256 tile, 32x32x16 MFMA.
// A: global->register (fragment-ordered WF, coalesced 1 KB wave loads,
// pipelined 1 tile ahead).  B: LDS (R5's Phi+XOR layout, 0 conflicts).
// FIX vs R9: empty compiler fences (asm ""::: "memory") pin the issue order
// glds-before-plain-loads inside each waitcnt region, so the counted vmcnt
// schedule is valid again (LLVM may otherwise hoist readonly global loads
// above global_load_lds — they don't alias LDS — which made VMC(8) drain
// A-loads instead of the B staging => incomplete LDS at barrier => NaN).
// ---------------------------------------------------------------------------
#define VMC(n) asm volatile("s_waitcnt vmcnt(" #n ")" ::: "memory")
#define FENCE() asm volatile("" ::: "memory")

__global__ __launch_bounds__(512, 2) void k_conv(
    const __hip_bfloat16* __restrict__ WF,   // [288][16][64][8] frag-ordered A
    const __hip_bfloat16* __restrict__ Xm,   // [16][66][66][512]
    const float* __restrict__ demod,         // [16][512]
    float* __restrict__ out)                 // [16][512][64][64]
{
  __shared__ __hip_bfloat16 lds[2][16384];   // [buf][256 rows][64 ch] B only

  const int orig = blockIdx.x;
  const int swz = (orig & 7)*64 + (orig >> 3);   // bijective XCD swizzle
  const int b  = swz >> 5;
  const int nt = (swz & 31) >> 1;
  const int mt = swz & 1;
  const int o0 = mt*256, y0 = nt*4;

  const int tid = threadIdx.x;
  const int l = tid & 63;
  const int w = tid >> 6;
  const int wm = w >> 2;       // 0..1
  const int wn = w & 3;        // 0..3

  // ---- B staging constants (linear LDS dest; Phi+swz folded into source) --
  const int srow = tid >> 3;
  const int tq   = (tid & 7) ^ (srow & 7);
  const char* XmC = (const char*)Xm;

  // ---- A stream constants ----
  const char* WFC = (const char*)WF + (size_t)(mt*8 + wm*4)*1024 + l*16;

  // ---- B frag-read constants (row=l&31, k-half=(l>>5)) ----
  const int rowb = ((l >> 5) << 4) | (l & 15);
  const int lb4  = (l >> 4) & 1;
  const int sB   = (l & 7) << 4;

  #define STAGE_B(tau, h, bfi) do { \
    const int kk_ = (tau) >> 3; \
    const int cb_ = ((tau) & 7) << 7; \
    const int dy_ = kk_/3 - 1, dx_ = kk_ - (kk_/3)*3 - 1; \
    _Pragma("unroll") \
    for (int it_ = 0; it_ < 2; ++it_) { \
      const int R_ = it_*64 + srow; \
      const int gr_ = (R_ & 0x6F) | ((tq & 1) << 4); \
      const int gc_ = ((tq & 6) | ((R_ >> 4) & 1)) << 4; \
      const int py_ = y0 + (h)*2 + (gr_ >> 6) + dy_ + 1; \
      const int px_ = (gr_ & 63) + dx_ + 1; \
      const char* src_ = XmC + ((size_t)((b*66 + py_)*66 + px_))*1024 + cb_ + gc_; \
      __builtin_amdgcn_global_load_lds( \
        (__attribute__((address_space(1))) void*)src_, \
        (__attribute__((address_space(3))) void*)((char*)&lds[bfi][0] + (h)*16384 + it_*8192 + w*1024), \
        16, 0, 0); \
    } \
  } while(0)

  #define STAGE_TILE_B(tau, bfi) do { \
    STAGE_B(tau, 0, bfi); STAGE_B(tau, 1, bfi); \
  } while(0)

  // issue 8 A-loads for half hh (phases 2hh, 2hh+1) of tile t
  #define ISSA(t, hh, dst) do { \
    _Pragma("unroll") \
    for (int k2_ = 0; k2_ < 2; ++k2_) { \
      const char* pA_ = WFC + (size_t)((t)*4 + (hh)*2 + k2_)*16384; \
      _Pragma("unroll") \
      for (int am_ = 0; am_ < 4; ++am_) \
        dst[k2_][am_] = *(const bf16x8*)(pA_ + am_*1024); \
    } \
  } while(0)

  // read 4 B frags (2 ks x 2 nh) of half hh from LDS buf
  #define RDB(Bb, hh, dst) do { \
    _Pragma("unroll") \
    for (int k2_ = 0; k2_ < 2; ++k2_) { \
      const int kc_ = ((((hh)*2 + k2_) << 1 | lb4) << 4) ^ sB; \
      _Pragma("unroll") \
      for (int nh_ = 0; nh_ < 2; ++nh_) \
        dst[k2_][nh_] = *(const bf16x8*)((Bb) + nh_*16384 + wn*4096 + rowb*128 + kc_); \
    } \
  } while(0)

  #define MM(k2, av, bv) do { \
    _Pragma("unroll") \
    for (int am_ = 0; am_ < 4; ++am_) \
      _Pragma("unroll") \
      for (int nh_ = 0; nh_ < 2; ++nh_) \
        acc[am_][nh_] = __builtin_amdgcn_mfma_f32_32x32x16_bf16( \
            av[k2][am_], bv[k2][nh_], acc[am_][nh_], 0, 0, 0); \
  } while(0)

  f32x16 acc[4][2] = {};
  bf16x8 aH0[2][4], aH1[2][4], b_[2][2];

  // prologue: B(0)->buf0 (4 glds), FENCE, A(0,H0) (8 loads); VMC(8) drains
  // the glds (guaranteed oldest thanks to the fence).
  STAGE_TILE_B(0, 0);
  FENCE();
  ISSA(0, 0, aH0);
  VMC(8);
  __builtin_amdgcn_s_barrier();

  // steady state per tile t (entry: [A(t,H0) x8] in flight, B(t) in buf t&1):
  //  R1: RDB(H0); +A(t,H1)[16]; VMC(8) -> A(t,H0) ready; MM0 MM1;
  //  R2: RDB(H1); +gldsB(t+1)[12]; FENCE; +A(t+1,H0)[20]; VMC(12) -> A(t,H1);
  //      MM2 MM3;
  //  R3: VMC(8) -> glds drained (oldest 4, order pinned); BAR.
  #pragma unroll 1
  for (int t = 0; t < 71; ++t) {
    const char* Bb_ = (const char*)&lds[t & 1][0];
    RDB(Bb_, 0, b_);
    ISSA(t, 1, aH1);
    VMC(8);
    MM(0, aH0, b_);
    MM(1, aH0, b_);
    RDB(Bb_, 1, b_);
    STAGE_TILE_B(t+1, (t & 1)^1);
    FENCE();
    ISSA(t+1, 0, aH0);
    VMC(12);
    MM(0, aH1, b_);
    MM(1, aH1, b_);
    VMC(8);
    __builtin_amdgcn_s_barrier();
  }
  // tile 71 (buf 1): no further staging (plain loads only -> deterministic)
  {
    const char* Bb_ = (const char*)&lds[1][0];
    RDB(Bb_, 0, b_);
    ISSA(71, 1, aH1);
    VMC(8);
    MM(0, aH0, b_);
    MM(1, aH0, b_);
    RDB(Bb_, 1, b_);
    VMC(0);
    MM(0, aH1, b_);
    MM(1, aH1, b_);
  }

  // epilogue: demod scale, NCHW fp32 store.
  // C/D 32x32 layout: col=l&31 (N), row=(r&3)+8*(r>>2)+4*(l>>5), r=g*4+j.
  const int lr = l & 31;
  #pragma unroll
  for (int am = 0; am < 4; ++am) {
    const int om = o0 + wm*128 + am*32 + ((l >> 5) << 2);
    #pragma unroll
    for (int NH = 0; NH < 2; ++NH) {
      const int nc = NH*128 + wn*32 + lr;
      const int y = y0 + (nc >> 6), xx = nc & 63;
      #pragma unroll
      for (int g = 0; g < 4; ++g) {
        const f32x4 dm = *(const f32x4*)(demod + b*512 + om + 8*g);
        float* op = out + (size_t)(b*512 + om + 8*g)*4096 + y*64 + xx;
        #pragma unroll
        for (int j = 0; j < 4; ++j)
          op[(size_t)j*4096] = acc[am][NH][g*4 + j] * dm[j];
      }
    }
  }
  #undef MM
  #undef RDB
  #undef ISSA
  #undef STAGE_TILE_B
  #undef STAGE_B
}

// ---------------------------------------------------------------------------
extern "C" void kernel_launch(void* const* d_in, const int* in_sizes, int n_in,
                              void* d_out, int out_size, void* d_ws, size_t ws_size,
                              hipStream_t stream)
{
  const float* x      = (const float*)d_in[0];
  const float* style  = (const float*)d_in[1];
  const float* weight = (const float*)d_in[2];
  const float* mod_w  = (const float*)d_in[3];
  const float* mod_b  = (const float*)d_in[4];
  float* out = (float*)d_out;

  char* ws = (char*)d_ws;
  float* s            = (float*)(ws);                  //  32 KB  [16][512]
  float* demod        = (float*)(ws + 32768);          //  32 KB  [16][512]
  float* w2           = (float*)(ws + 65536);          //   1 MB  [512][512]
  __hip_bfloat16* WF  = (__hip_bfloat16*)(ws + 1114112);   // 4.5 MB [288][16][64][8]
  __hip_bfloat16* Xm  = (__hip_bfloat16*)(ws + 5832704);   // 71.4 MB [16][66][66][512]

  k_style <<<16,    512, 0, stream>>>(style, mod_w, mod_b, s);
  k_weight<<<512,   256, 0, stream>>>(weight, w2, WF);
  k_demod <<<16,    256, 0, stream>>>(s, w2, demod);
  k_xm    <<<16384, 256, 0, stream>>>(x, s, Xm);
  k_conv  <<<512,   512, 0, stream>>>(WF, Xm, demod, out);
}

// Round 11
// 392.571 us; speedup vs baseline: 1.0505x; 1.0505x over previous
//
#include <hip/hip_runtime.h>
#include <hip/hip_bf16.h>
#include <cstdint>
#include <cstddef>

typedef __bf16 bf16x8 __attribute__((ext_vector_type(8)));
typedef float f32x4 __attribute__((ext_vector_type(4)));
typedef float f32x16 __attribute__((ext_vector_type(16)));

#define MOD_SCALE 1.4731391e-02f   // 1/sqrt(512*9)
#define EPSF 1e-8f

// ---------------------------------------------------------------------------
// K1: s[b][i] = dot(style[b], mod_w[i]) + mod_b[i]
// ---------------------------------------------------------------------------
__global__ __launch_bounds__(512) void k_style(
    const float* __restrict__ style, const float* __restrict__ mod_w,
    const float* __restrict__ mod_b, float* __restrict__ s)
{
  __shared__ float st[512];
  const int b = blockIdx.x, i = threadIdx.x;
  st[i] = style[b*512 + i];
  __syncthreads();
  const float4* mw = (const float4*)(mod_w + (size_t)i*512);
  float acc = 0.f;
  #pragma unroll 8
  for (int j = 0; j < 128; ++j) {
    float4 v = mw[j];
    acc += v.x*st[4*j] + v.y*st[4*j+1] + v.z*st[4*j+2] + v.w*st[4*j+3];
  }
  s[b*512 + i] = acc + mod_b[i];
}

// ---------------------------------------------------------------------------
// K2: w2[o][i] = sum_kk weight^2 ; Wb[kk][o][i] = bf16(SCALE*weight)
// ---------------------------------------------------------------------------
__global__ __launch_bounds__(256) void k_weight(
    const float* __restrict__ weight, float* __restrict__ w2,
    __hip_bfloat16* __restrict__ Wb)
{
  const int o = blockIdx.x, t = threadIdx.x;
  #pragma unroll
  for (int h = 0; h < 2; ++h) {
    const int i = t + h*256;
    const float* wp = weight + ((size_t)o*512 + i)*9;
    float sq = 0.f;
    #pragma unroll
    for (int kk = 0; kk < 9; ++kk) {
      float v = wp[kk];
      sq += v*v;
      Wb[((size_t)kk*512 + o)*512 + i] = __float2bfloat16(v * MOD_SCALE);
    }
    w2[(size_t)o*512 + i] = sq;
  }
}

// ---------------------------------------------------------------------------
// K2b: demod[b][o] = rsqrt(SCALE^2 * sum_i s[b][i]^2 * w2[o][i] + eps)
// ---------------------------------------------------------------------------
__global__ __launch_bounds__(256) void k_demod(
    const float* __restrict__ s, const float* __restrict__ w2,
    float* __restrict__ demod)
{
  __shared__ float s2[512];
  const int b = blockIdx.x, t = threadIdx.x;
  {
    float a = s[b*512 + t];        s2[t]     = a*a;
    float c = s[b*512 + t + 256];  s2[t+256] = c*c;
  }
  __syncthreads();
  #pragma unroll
  for (int h = 0; h < 2; ++h) {
    const int o = t + h*256;
    const float4* wp = (const float4*)(w2 + (size_t)o*512);
    float acc = 0.f;
    #pragma unroll 8
    for (int j = 0; j < 128; ++j) {
      float4 v = wp[j];
      acc += v.x*s2[4*j] + v.y*s2[4*j+1] + v.z*s2[4*j+2] + v.w*s2[4*j+3];
    }
    demod[b*512 + o] = rsqrtf(MOD_SCALE*MOD_SCALE*acc + EPSF);
  }
}

// ---------------------------------------------------------------------------
// K3: Xm[b][py][px][i] = bf16(s[b][i] * x[b][i][py-1][px-1]); writes own halo.
// ---------------------------------------------------------------------------
__global__ __launch_bounds__(256) void k_xm(
    const float* __restrict__ x, const float* __restrict__ s,
    __hip_bfloat16* __restrict__ Xm)
{
  __shared__ __hip_bfloat16 T[64][40];
  const int bid = blockIdx.x;
  const int cb = bid & 15, y = (bid >> 4) & 63, b = bid >> 10;
  const int ic0 = cb*32;
  const int t = threadIdx.x;
  const int i = t >> 3, x0 = (t & 7)*8;
  const float sv = s[b*512 + ic0 + i];
  const float4* xp = (const float4*)(x + (size_t)(b*512 + ic0 + i)*4096 + y*64 + x0);
  float4 v0 = xp[0], v1 = xp[1];
  float vals[8] = {v0.x, v0.y, v0.z, v0.w, v1.x, v1.y, v1.z, v1.w};
  #pragma unroll
  for (int j = 0; j < 8; ++j) T[x0+j][i] = __float2bfloat16(vals[j]*sv);

  const float4 z4 = make_float4(0.f, 0.f, 0.f, 0.f);
  if (t < 8) {
    const int side = t >> 2, j = t & 3;
    float4* hz = (float4*)(Xm + (((size_t)(b*66 + (y+1))*66 + side*65)*512 + ic0 + j*8));
    *hz = z4;
  }
  if (y == 0) {
    for (int idx = t; idx < 264; idx += 256) {
      const int px = idx >> 2, j = idx & 3;
      float4* hz = (float4*)(Xm + (((size_t)(b*66 + 0)*66 + px)*512 + ic0 + j*8));
      *hz = z4;
    }
  }
  if (y == 63) {
    for (int idx = t; idx < 264; idx += 256) {
      const int px = idx >> 2, j = idx & 3;
      float4* hz = (float4*)(Xm + (((size_t)(b*66 + 65)*66 + px)*512 + ic0 + j*8));
      *hz = z4;
    }
  }

  __syncthreads();
  const int p = t >> 2, c = (t & 3)*8;
  __hip_bfloat16* dst = Xm + (((size_t)(b*66 + (y+1))*66 + (p+1))*512 + ic0 + c);
  *(float4*)dst = *(const float4*)&T[p][c];
}

// ---------------------------------------------------------------------------
// K4: R5 kernel (best verified: 289 us, 0 conflicts) + WAVE ANTI-PHASING:
// waves with hx=wm=1 traverse the tile's quadrants relabeled by XOR
// (Mhalf^1, Nhalf^1).  On round-robin wave->SIMD mapping, a SIMD's two
// resident waves (w, w+4) differ exactly in wm, so the twins are half a
// tile out of phase: one feeds the LDS pipe while the other feeds the
// matrix pipe, breaking the issue-lockstep that serialized the two pipes
// in R5-R10.  Reads within a tile target a stable buffer -> any per-wave
// order is race-free; acc indices stay static (relabel applied to LDS
// addresses + epilogue coordinates only).
// ---------------------------------------------------------------------------
#define VMC(n) asm volatile("s_waitcnt vmcnt(" #n ")" ::: "memory")

__global__ __launch_bounds__(512, 2) void k_conv(
    const __hip_bfloat16* __restrict__ Wb,   // [9][512][512]
    const __hip_bfloat16* __restrict__ Xm,   // [16][66][66][512]
    const float* __restrict__ demod,         // [16][512]
    float* __restrict__ out)                 // [16][512][64][64]
{
  __shared__ __hip_bfloat16 lds[2][2][16384];   // [buf][A=0/B=1][256*64]

  const int orig = blockIdx.x;
  const int swz = (orig & 7)*64 + (orig >> 3);   // bijective XCD swizzle (512%8==0)
  const int b  = swz >> 5;
  const int nt = (swz & 31) >> 1;
  const int mt = swz & 1;
  const int o0 = mt*256, y0 = nt*4;

  const int tid = threadIdx.x;
  const int l = tid & 63;
  const int w = tid >> 6;
  const int wm = w >> 2;       // 0..1
  const int wn = w & 3;        // 0..3
  const int hx = wm;           // anti-phase relabel bit (twins w, w+4 differ)

  // ---- staging constants: linear LDS dest; Phi+swz folded into source ----
  const int srow = tid >> 3;                      // 0..63 (physical row mod 64)
  const int tq   = (tid & 7) ^ (srow & 7);        // t = q ^ (R&7)
  const char* WbC = (const char*)Wb;
  const char* XmC = (const char*)Xm;

  // ---- frag-read constants (32x32 frag: row=l&31, k-half=(l>>5)) ----
  const int rowb = ((l >> 5) << 4) | (l & 15);    // physical row in 32-group
  const int lb4  = (l >> 4) & 1;
  const int sB   = (l & 7) << 4;

  #define STAGE_A(tau, h, bfi) do { \
    const int kk_ = (tau) >> 3; \
    const int cb_ = ((tau) & 7) << 7; \
    _Pragma("unroll") \
    for (int it_ = 0; it_ < 2; ++it_) { \
      const int R_ = it_*64 + srow; \
      const int gr_ = (R_ & 0x6F) | ((tq & 1) << 4); \
      const int gc_ = ((tq & 6) | ((R_ >> 4) & 1)) << 4; \
      const char* src_ = WbC + (size_t)(kk_*512 + o0 + (h)*128 + gr_)*1024 + cb_ + gc_; \
      __builtin_amdgcn_global_load_lds( \
        (__attribute__((address_space(1))) void*)src_, \
        (__attribute__((address_space(3))) void*)((char*)&lds[bfi][0][0] + (h)*16384 + it_*8192 + w*1024), \
        16, 0, 0); \
    } \
  } while(0)

  #define STAGE_B(tau, h, bfi) do { \
    const int kk_ = (tau) >> 3; \
    const int cb_ = ((tau) & 7) << 7; \
    const int dy_ = kk_/3 - 1, dx_ = kk_ - (kk_/3)*3 - 1; \
    _Pragma("unroll") \
    for (int it_ = 0; it_ < 2; ++it_) { \
      const int R_ = it_*64 + srow; \
      const int gr_ = (R_ & 0x6F) | ((tq & 1) << 4); \
      const int gc_ = ((tq & 6) | ((R_ >> 4) & 1)) << 4; \
      const int py_ = y0 + (h)*2 + (gr_ >> 6) + dy_ + 1; \
      const int px_ = (gr_ & 63) + dx_ + 1; \
      const char* src_ = XmC + ((size_t)((b*66 + py_)*66 + px_))*1024 + cb_ + gc_; \
      __builtin_amdgcn_global_load_lds( \
        (__attribute__((address_space(1))) void*)src_, \
        (__attribute__((address_space(3))) void*)((char*)&lds[bfi][1][0] + (h)*16384 + it_*8192 + w*1024), \
        16, 0, 0); \
    } \
  } while(0)

  // reads: logical half (MH/NH) -> physical half (MH^hx / NH^hx)
  #define RD_A(Ab, MH, dst) do { \
    _Pragma("unroll") \
    for (int mi_ = 0; mi_ < 2; ++mi_) \
      _Pragma("unroll") \
      for (int ks_ = 0; ks_ < 4; ++ks_) \
        dst[mi_][ks_] = *(const bf16x8*)((Ab) + ((MH)^hx)*16384 + wm*8192 + mi_*4096 \
            + rowb*128 + (((((ks_<<1)|lb4)) << 4) ^ sB)); \
  } while(0)

  #define RD_B(Bb, NH, dst) do { \
    _Pragma("unroll") \
    for (int ks_ = 0; ks_ < 4; ++ks_) \
      dst[ks_] = *(const bf16x8*)((Bb) + ((NH)^hx)*16384 + wn*4096 \
          + rowb*128 + (((((ks_<<1)|lb4)) << 4) ^ sB)); \
  } while(0)

  #define MFMAQ(AM0, dstA, NH, dstB) do { \
    _Pragma("unroll") \
    for (int ks_ = 0; ks_ < 4; ++ks_) \
      _Pragma("unroll") \
      for (int mi_ = 0; mi_ < 2; ++mi_) \
        acc[(AM0)+mi_][NH] = __builtin_amdgcn_mfma_f32_32x32x16_bf16( \
            dstA[mi_][ks_], dstB[ks_], acc[(AM0)+mi_][NH], 0, 0, 0); \
  } while(0)

  // One K-tile = 4 phases: P1:Q00(rd A0,B0) P2:Q01(rd B1) P3:Q11(rd A1) P4:Q10
  // (quadrants are LOGICAL; hx relabels the physical halves per wave).
  #define TILE(BFI, S1, S2, S3, S4, VM1, VM4) do { \
    const char* Ab_ = (const char*)&lds[BFI][0][0]; \
    const char* Bb_ = (const char*)&lds[BFI][1][0]; \
    bf16x8 a0_[2][4], a1_[2][4], b0_[4], b1_[4]; \
    /* P1 */ \
    RD_A(Ab_, 0, a0_); RD_B(Bb_, 0, b0_); \
    S1; \
    __builtin_amdgcn_s_barrier(); \
    __builtin_amdgcn_s_setprio(1); MFMAQ(0, a0_, 0, b0_); __builtin_amdgcn_s_setprio(0); \
    VM1; \
    __builtin_amdgcn_s_barrier(); \
    /* P2 */ \
    RD_B(Bb_, 1, b1_); \
    S2; \
    __builtin_amdgcn_s_barrier(); \
    __builtin_amdgcn_s_setprio(1); MFMAQ(0, a0_, 1, b1_); __builtin_amdgcn_s_setprio(0); \
    __builtin_amdgcn_s_barrier(); \
    /* P3 */ \
    RD_A(Ab_, 1, a1_); \
    S3; \
    __builtin_amdgcn_s_barrier(); \
    __builtin_amdgcn_s_setprio(1); MFMAQ(2, a1_, 1, b1_); __builtin_amdgcn_s_setprio(0); \
    __builtin_amdgcn_s_barrier(); \
    /* P4 */ \
    S4; \
    __builtin_amdgcn_s_barrier(); \
    __builtin_amdgcn_s_setprio(1); MFMAQ(2, a1_, 0, b0_); __builtin_amdgcn_s_setprio(0); \
    VM4; \
    __builtin_amdgcn_s_barrier(); \
  } while(0)

  f32x16 acc[4][2] = {};

  // prologue: tile0 complete + B(1,h0), A(1,h1); leave 2 half-tiles in flight
  STAGE_A(0, 0, 0); STAGE_A(0, 1, 0); STAGE_B(0, 0, 0); STAGE_B(0, 1, 0);
  STAGE_B(1, 0, 1); STAGE_A(1, 1, 1);
  VMC(4);
  __builtin_amdgcn_s_barrier();

  #pragma unroll 1
  for (int tt = 0; tt < 35; ++tt) {
    const int t = tt*2;
    TILE(0, STAGE_A(t+1,0,1), STAGE_B(t+1,1,1), STAGE_B(t+2,0,0), STAGE_A(t+2,1,0),
            VMC(6), VMC(6));
    TILE(1, STAGE_A(t+2,0,0), STAGE_B(t+2,1,0), STAGE_B(t+3,0,1), STAGE_A(t+3,1,1),
            VMC(6), VMC(6));
  }
  // tail: t=70,71
  TILE(0, STAGE_A(71,0,1), STAGE_B(71,1,1), (void)0, (void)0, VMC(6), VMC(2));
  TILE(1, (void)0, (void)0, (void)0, (void)0, VMC(0), (void)0);

  // epilogue: demod scale, NCHW fp32 store (physical coords carry ^hx).
  // C/D 32x32 layout: col=l&31 (N), row=(r&3)+8*(r>>2)+4*(l>>5), r=g*4+j.
  const int lr = l & 31;
  #pragma unroll
  for (int am = 0; am < 4; ++am) {
    const int om = o0 + ((am >> 1)^hx)*128 + wm*64 + (am & 1)*32 + ((l >> 5) << 2);
    #pragma unroll
    for (int NH = 0; NH < 2; ++NH) {
      const int nc = ((NH)^hx)*128 + wn*32 + lr;
      const int y = y0 + (nc >> 6), xx = nc & 63;
      #pragma unroll
      for (int g = 0; g < 4; ++g) {
        const f32x4 dm = *(const f32x4*)(demod + b*512 + om + 8*g);
        float* op = out + (size_t)(b*512 + om + 8*g)*4096 + y*64 + xx;
        #pragma unroll
        for (int j = 0; j < 4; ++j)
          op[(size_t)j*4096] = acc[am][NH][g*4 + j] * dm[j];
      }
    }
  }
  #undef TILE
  #undef MFMAQ
  #undef RD_A
  #undef RD_B
  #undef STAGE_A
  #undef STAGE_B
}

// ---------------------------------------------------------------------------
extern "C" void kernel_launch(void* const* d_in, const int* in_sizes, int n_in,
                              void* d_out, int out_size, void* d_ws, size_t ws_size,
                              hipStream_t stream)
{
  const float* x      = (const float*)d_in[0];
  const float* style  = (const float*)d_in[1];
  const float* weight = (const float*)d_in[2];
  const float* mod_w  = (const float*)d_in[3];
  const float* mod_b  = (const float*)d_in[4];
  float* out = (float*)d_out;

  char* ws = (char*)d_ws;
  float* s            = (float*)(ws);                  //  32 KB  [16][512]
  float* demod        = (float*)(ws + 32768);          //  32 KB  [16][512]
  float* w2           = (float*)(ws + 65536);          //   1 MB  [512][512]
  __hip_bfloat16* Wb  = (__hip_bfloat16*)(ws + 1114112);   // 4.5 MB [9][512][512]
  __hip_bfloat16* Xm  = (__hip_bfloat16*)(ws + 5832704);   // 71.4 MB [16][66][66][512]

  k_style <<<16,    512, 0, stream>>>(style, mod_w, mod_b, s);
  k_weight<<<512,   256, 0, stream>>>(weight, w2, Wb);
  k_demod <<<16,    256, 0, stream>>>(s, w2, demod);
  k_xm    <<<16384, 256, 0, stream>>>(x, s, Xm);
  k_conv  <<<512,   512, 0, stream>>>(Wb, Xm, demod, out);
}

// Round 12
// 385.185 us; speedup vs baseline: 1.0706x; 1.0192x over previous
//
#include <hip/hip_runtime.h>
#include <hip/hip_bf16.h>
#include <cstdint>
#include <cstddef>

typedef __bf16 bf16x8 __attribute__((ext_vector_type(8)));
typedef float f32x4 __attribute__((ext_vector_type(4)));
typedef float f32x16 __attribute__((ext_vector_type(16)));

#define MOD_SCALE 1.4731391e-02f   // 1/sqrt(512*9)
#define EPSF 1e-8f

// ---------------------------------------------------------------------------
// K1: s[b][i] = dot(style[b], mod_w[i]) + mod_b[i]
// ---------------------------------------------------------------------------
__global__ __launch_bounds__(512) void k_style(
    const float* __restrict__ style, const float* __restrict__ mod_w,
    const float* __restrict__ mod_b, float* __restrict__ s)
{
  __shared__ float st[512];
  const int b = blockIdx.x, i = threadIdx.x;
  st[i] = style[b*512 + i];
  __syncthreads();
  const float4* mw = (const float4*)(mod_w + (size_t)i*512);
  float acc = 0.f;
  #pragma unroll 8
  for (int j = 0; j < 128; ++j) {
    float4 v = mw[j];
    acc += v.x*st[4*j] + v.y*st[4*j+1] + v.z*st[4*j+2] + v.w*st[4*j+3];
  }
  s[b*512 + i] = acc + mod_b[i];
}

// ---------------------------------------------------------------------------
// K2: w2[o][i] = sum_kk weight^2 ; Wb[kk][o][i] = bf16(SCALE*weight)
// ---------------------------------------------------------------------------
__global__ __launch_bounds__(256) void k_weight(
    const float* __restrict__ weight, float* __restrict__ w2,
    __hip_bfloat16* __restrict__ Wb)
{
  const int o = blockIdx.x, t = threadIdx.x;
  #pragma unroll
  for (int h = 0; h < 2; ++h) {
    const int i = t + h*256;
    const float* wp = weight + ((size_t)o*512 + i)*9;
    float sq = 0.f;
    #pragma unroll
    for (int kk = 0; kk < 9; ++kk) {
      float v = wp[kk];
      sq += v*v;
      Wb[((size_t)kk*512 + o)*512 + i] = __float2bfloat16(v * MOD_SCALE);
    }
    w2[(size_t)o*512 + i] = sq;
  }
}

// ---------------------------------------------------------------------------
// K2b: demod[b][o] = rsqrt(SCALE^2 * sum_i s[b][i]^2 * w2[o][i] + eps)
// ---------------------------------------------------------------------------
__global__ __launch_bounds__(256) void k_demod(
    const float* __restrict__ s, const float* __restrict__ w2,
    float* __restrict__ demod)
{
  __shared__ float s2[512];
  const int b = blockIdx.x, t = threadIdx.x;
  {
    float a = s[b*512 + t];        s2[t]     = a*a;
    float c = s[b*512 + t + 256];  s2[t+256] = c*c;
  }
  __syncthreads();
  #pragma unroll
  for (int h = 0; h < 2; ++h) {
    const int o = t + h*256;
    const float4* wp = (const float4*)(w2 + (size_t)o*512);
    float acc = 0.f;
    #pragma unroll 8
    for (int j = 0; j < 128; ++j) {
      float4 v = wp[j];
      acc += v.x*s2[4*j] + v.y*s2[4*j+1] + v.z*s2[4*j+2] + v.w*s2[4*j+3];
    }
    demod[b*512 + o] = rsqrtf(MOD_SCALE*MOD_SCALE*acc + EPSF);
  }
}

// ---------------------------------------------------------------------------
// K3: Xm[b][py][px][i] = bf16(s[b][i] * x[b][i][py-1][px-1]); writes own halo.
// ---------------------------------------------------------------------------
__global__ __launch_bounds__(256) void k_xm(
    const float* __restrict__ x, const float* __restrict__ s,
    __hip_bfloat16* __restrict__ Xm)
{
  __shared__ __hip_bfloat16 T[64][40];
  const int bid = blockIdx.x;
  const int cb = bid & 15, y = (bid >> 4) & 63, b = bid >> 10;
  const int ic0 = cb*32;
  const int t = threadIdx.x;
  const int i = t >> 3, x0 = (t & 7)*8;
  const float sv = s[b*512 + ic0 + i];
  const float4* xp = (const float4*)(x + (size_t)(b*512 + ic0 + i)*4096 + y*64 + x0);
  float4 v0 = xp[0], v1 = xp[1];
  float vals[8] = {v0.x, v0.y, v0.z, v0.w, v1.x, v1.y, v1.z, v1.w};
  #pragma unroll
  for (int j = 0; j < 8; ++j) T[x0+j][i] = __float2bfloat16(vals[j]*sv);

  const float4 z4 = make_float4(0.f, 0.f, 0.f, 0.f);
  if (t < 8) {
    const int side = t >> 2, j = t & 3;
    float4* hz = (float4*)(Xm + (((size_t)(b*66 + (y+1))*66 + side*65)*512 + ic0 + j*8));
    *hz = z4;
  }
  if (y == 0) {
    for (int idx = t; idx < 264; idx += 256) {
      const int px = idx >> 2, j = idx & 3;
      float4* hz = (float4*)(Xm + (((size_t)(b*66 + 0)*66 + px)*512 + ic0 + j*8));
      *hz = z4;
    }
  }
  if (y == 63) {
    for (int idx = t; idx < 264; idx += 256) {
      const int px = idx >> 2, j = idx & 3;
      float4* hz = (float4*)(Xm + (((size_t)(b*66 + 65)*66 + px)*512 + ic0 + j*8));
      *hz = z4;
    }
  }

  __syncthreads();
  const int p = t >> 2, c = (t & 3)*8;
  __hip_bfloat16* dst = Xm + (((size_t)(b*66 + (y+1))*66 + (p+1))*512 + ic0 + c);
  *(float4*)dst = *(const float4*)&T[p][c];
}

// ---------------------------------------------------------------------------
// K4: R5 kernel (best verified) + HOISTED STAGING ADDRESSES: every glds
// source = per-thread 32-bit invariant offset (precomputed: aoff/boff) +
// wave-uniform scalar u(tau,h) computed on SALU.  Deletes the per-stage
// 64-bit VALU address construction (~750 cyc/tile residual seen as
// VALUBusy 17%).  Addresses algebraically identical to R5; schedule, VMC
// counts, Phi+XOR layout (0 conflicts), epilogue unchanged.
// ---------------------------------------------------------------------------
#define VMC(n) asm volatile("s_waitcnt vmcnt(" #n ")" ::: "memory")

__global__ __launch_bounds__(512, 2) void k_conv(
    const __hip_bfloat16* __restrict__ Wb,   // [9][512][512]
    const __hip_bfloat16* __restrict__ Xm,   // [16][66][66][512]
    const float* __restrict__ demod,         // [16][512]
    float* __restrict__ out)                 // [16][512][64][64]
{
  __shared__ __hip_bfloat16 lds[2][2][16384];   // [buf][A=0/B=1][256*64]

  const int orig = blockIdx.x;
  const int swz = (orig & 7)*64 + (orig >> 3);   // bijective XCD swizzle (512%8==0)
  const int b  = swz >> 5;
  const int nt = (swz & 31) >> 1;
  const int mt = swz & 1;
  const int o0 = mt*256, y0 = nt*4;

  const int tid = threadIdx.x;
  const int l = tid & 63;
  const int w = tid >> 6;
  const int wm = w >> 2;       // 0..1
  const int wn = w & 3;        // 0..3

  // ---- staging: per-thread invariant offsets (Phi+swz folded) ----
  const int srow = tid >> 3;
  const int tq   = (tid & 7) ^ (srow & 7);
  const char* WbC = (const char*)Wb;
  const char* XmC = (const char*)Xm;

  int aoff[2], boff[2], ldst[2];
  #pragma unroll
  for (int it = 0; it < 2; ++it) {
    const int R  = it*64 + srow;
    const int gr = (R & 0x6F) | ((tq & 1) << 4);
    const int gc = ((tq & 6) | ((R >> 4) & 1)) << 4;
    aoff[it] = (o0 + gr)*1024 + gc;                                   // + u_a
    boff[it] = (((b*66 + y0 + 1 + (gr >> 6))*66) + (gr & 63) + 1)*1024 + gc; // + u_b
    ldst[it] = it*8192 + w*1024;
  }

  // ---- frag-read constants (32x32 frag: row=l&31, k-half=(l>>5)) ----
  const int rowb = ((l >> 5) << 4) | (l & 15);
  const int lb4  = (l >> 4) & 1;
  const int sB   = (l & 7) << 4;

  // wave-uniform stage scalars (SALU): tau -> tap kk, channel block cb
  #define STAGE_A(tau, h, bfi) do { \
    const int u_ = ((tau) >> 3)*524288 + (h)*131072 + (((tau) & 7) << 7); \
    _Pragma("unroll") \
    for (int it_ = 0; it_ < 2; ++it_) \
      __builtin_amdgcn_global_load_lds( \
        (__attribute__((address_space(1))) void*)(WbC + u_ + aoff[it_]), \
        (__attribute__((address_space(3))) void*)((char*)&lds[bfi][0][0] + (h)*16384 + ldst[it_]), \
        16, 0, 0); \
  } while(0)

  #define STAGE_B(tau, h, bfi) do { \
    const int kk_ = (tau) >> 3; \
    const int dy_ = kk_/3 - 1, dx_ = kk_ - (kk_/3)*3 - 1; \
    const int u_ = (((h)*2 + dy_)*66 + dx_)*1024 + (((tau) & 7) << 7); \
    _Pragma("unroll") \
    for (int it_ = 0; it_ < 2; ++it_) \
      __builtin_amdgcn_global_load_lds( \
        (__attribute__((address_space(1))) void*)(XmC + u_ + boff[it_]), \
        (__attribute__((address_space(3))) void*)((char*)&lds[bfi][1][0] + (h)*16384 + ldst[it_]), \
        16, 0, 0); \
  } while(0)

  #define RD_A(Ab, MH, dst) do { \
    _Pragma("unroll") \
    for (int mi_ = 0; mi_ < 2; ++mi_) \
      _Pragma("unroll") \
      for (int ks_ = 0; ks_ < 4; ++ks_) \
        dst[mi_][ks_] = *(const bf16x8*)((Ab) + (MH)*16384 + wm*8192 + mi_*4096 \
            + rowb*128 + (((((ks_<<1)|lb4)) << 4) ^ sB)); \
  } while(0)

  #define RD_B(Bb, NH, dst) do { \
    _Pragma("unroll") \
    for (int ks_ = 0; ks_ < 4; ++ks_) \
      dst[ks_] = *(const bf16x8*)((Bb) + (NH)*16384 + wn*4096 \
          + rowb*128 + (((((ks_<<1)|lb4)) << 4) ^ sB)); \
  } while(0)

  #define MFMAQ(AM0, dstA, NH, dstB) do { \
    _Pragma("unroll") \
    for (int ks_ = 0; ks_ < 4; ++ks_) \
      _Pragma("unroll") \
      for (int mi_ = 0; mi_ < 2; ++mi_) \
        acc[(AM0)+mi_][NH] = __builtin_amdgcn_mfma_f32_32x32x16_bf16( \
            dstA[mi_][ks_], dstB[ks_], acc[(AM0)+mi_][NH], 0, 0, 0); \
  } while(0)

  // One K-tile = 4 phases: P1:Q00(rd A0,B0) P2:Q01(rd B1) P3:Q11(rd A1) P4:Q10.
  #define TILE(BFI, S1, S2, S3, S4, VM1, VM4) do { \
    const char* Ab_ = (const char*)&lds[BFI][0][0]; \
    const char* Bb_ = (const char*)&lds[BFI][1][0]; \
    bf16x8 a0_[2][4], a1_[2][4], b0_[4], b1_[4]; \
    /* P1 */ \
    RD_A(Ab_, 0, a0_); RD_B(Bb_, 0, b0_); \
    S1; \
    __builtin_amdgcn_s_barrier(); \
    __builtin_amdgcn_s_setprio(1); MFMAQ(0, a0_, 0, b0_); __builtin_amdgcn_s_setprio(0); \
    VM1; \
    __builtin_amdgcn_s_barrier(); \
    /* P2 */ \
    RD_B(Bb_, 1, b1_); \
    S2; \
    __builtin_amdgcn_s_barrier(); \
    __builtin_amdgcn_s_setprio(1); MFMAQ(0, a0_, 1, b1_); __builtin_amdgcn_s_setprio(0); \
    __builtin_amdgcn_s_barrier(); \
    /* P3 */ \
    RD_A(Ab_, 1, a1_); \
    S3; \
    __builtin_amdgcn_s_barrier(); \
    __builtin_amdgcn_s_setprio(1); MFMAQ(2, a1_, 1, b1_); __builtin_amdgcn_s_setprio(0); \
    __builtin_amdgcn_s_barrier(); \
    /* P4 */ \
    S4; \
    __builtin_amdgcn_s_barrier(); \
    __builtin_amdgcn_s_setprio(1); MFMAQ(2, a1_, 0, b0_); __builtin_amdgcn_s_setprio(0); \
    VM4; \
    __builtin_amdgcn_s_barrier(); \
  } while(0)

  f32x16 acc[4][2] = {};

  // prologue: tile0 complete + B(1,h0), A(1,h1); leave 2 half-tiles in flight
  STAGE_A(0, 0, 0); STAGE_A(0, 1, 0); STAGE_B(0, 0, 0); STAGE_B(0, 1, 0);
  STAGE_B(1, 0, 1); STAGE_A(1, 1, 1);
  VMC(4);
  __builtin_amdgcn_s_barrier();

  #pragma unroll 1
  for (int tt = 0; tt < 35; ++tt) {
    const int t = tt*2;
    TILE(0, STAGE_A(t+1,0,1), STAGE_B(t+1,1,1), STAGE_B(t+2,0,0), STAGE_A(t+2,1,0),
            VMC(6), VMC(6));
    TILE(1, STAGE_A(t+2,0,0), STAGE_B(t+2,1,0), STAGE_B(t+3,0,1), STAGE_A(t+3,1,1),
            VMC(6), VMC(6));
  }
  // tail: t=70,71
  TILE(0, STAGE_A(71,0,1), STAGE_B(71,1,1), (void)0, (void)0, VMC(6), VMC(2));
  TILE(1, (void)0, (void)0, (void)0, (void)0, VMC(0), (void)0);

  // epilogue: demod scale, NCHW fp32 store.
  // C/D 32x32 layout: col=l&31 (N), row=(r&3)+8*(r>>2)+4*(l>>5), r=g*4+j.
  const int lr = l & 31;
  #pragma unroll
  for (int am = 0; am < 4; ++am) {
    const int om = o0 + (am >> 1)*128 + wm*64 + (am & 1)*32 + ((l >> 5) << 2);
    #pragma unroll
    for (int NH = 0; NH < 2; ++NH) {
      const int nc = NH*128 + wn*32 + lr;
      const int y = y0 + (nc >> 6), xx = nc & 63;
      #pragma unroll
      for (int g = 0; g < 4; ++g) {
        const f32x4 dm = *(const f32x4*)(demod + b*512 + om + 8*g);
        float* op = out + (size_t)(b*512 + om + 8*g)*4096 + y*64 + xx;
        #pragma unroll
        for (int j = 0; j < 4; ++j)
          op[(size_t)j*4096] = acc[am][NH][g*4 + j] * dm[j];
      }
    }
  }
  #undef TILE
  #undef MFMAQ
  #undef RD_A
  #undef RD_B
  #undef STAGE_A
  #undef STAGE_B
}

// ---------------------------------------------------------------------------
extern "C" void kernel_launch(void* const* d_in, const int* in_sizes, int n_in,
                              void* d_out, int out_size, void* d_ws, size_t ws_size,
                              hipStream_t stream)
{
  const float* x      = (const float*)d_in[0];
  const float* style  = (const float*)d_in[1];
  const float* weight = (const float*)d_in[2];
  const float* mod_w  = (const float*)d_in[3];
  const float* mod_b  = (const float*)d_in[4];
  float* out = (float*)d_out;

  char* ws = (char*)d_ws;
  float* s            = (float*)(ws);                  //  32 KB  [16][512]
  float* demod        = (float*)(ws + 32768);          //  32 KB  [16][512]
  float* w2           = (float*)(ws + 65536);          //   1 MB  [512][512]
  __hip_bfloat16* Wb  = (__hip_bfloat16*)(ws + 1114112);   // 4.5 MB [9][512][512]
  __hip_bfloat16* Xm  = (__hip_bfloat16*)(ws + 5832704);   // 71.4 MB [16][66][66][512]

  k_style <<<16,    512, 0, stream>>>(style, mod_w, mod_b, s);
  k_weight<<<512,   256, 0, stream>>>(weight, w2, Wb);
  k_demod <<<16,    256, 0, stream>>>(s, w2, demod);
  k_xm    <<<16384, 256, 0, stream>>>(x, s, Xm);
  k_conv  <<<512,   512, 0, stream>>>(Wb, Xm, demod, out);
}